// Round 2
// baseline (32880.869 us; speedup 1.0000x reference)
//
#include <hip/hip_runtime.h>

#define BATCH 65536
#define T 500
#define HID 64
#define GHID 52

__device__ __forceinline__ float fast_tanh(float x) {
    // tanh(x) = 1 - 2/(exp(2x)+1); exact saturation at +/-inf
    float e = __expf(2.0f * x);
    return 1.0f - 2.0f / (e + 1.0f);
}

__device__ __forceinline__ float fast_softplus(float x) {
    // softplus(x) = max(x,0) + log(1 + exp(-|x|)) -- overflow-safe
    float e = __expf(-fabsf(x));
    return fmaxf(x, 0.0f) + __logf(1.0f + e);
}

// 2 -> DIM -> DIM -> 2 MLP for one sample, cooperatively computed by the 4
// "quarters" (lane groups of 16) of a wave. Lane quarter q owns hidden units
// [q*CHUNK, (q+1)*CHUNK). Hidden-layer operands are gathered from the other
// quarters with shfl_xor; the 2 outputs are butterfly-reduced so ALL lanes
// end with bit-identical o0/o1 (IEEE add is commutative -> replication-safe).
template<int DIM, int CHUNK>
__device__ __forceinline__ void mlp4(
    float ya, float yb, int q,
    const float* __restrict__ w1, const float* __restrict__ b1,
    const float* __restrict__ w2, const float* __restrict__ b2,
    const float* __restrict__ w3, const float* __restrict__ b3,
    float& o0, float& o1)
{
    const int row0 = q * CHUNK;

    // layer 1: my CHUNK hidden units
    float h[CHUNK];
    #pragma unroll
    for (int i = 0; i < CHUNK; ++i) {
        int r = row0 + i;
        float pre = fmaf(w1[2 * r], ya, fmaf(w1[2 * r + 1], yb, b1[r]));
        h[i] = fast_tanh(pre);
    }

    // layer 2: acc[j] = b2[row0+j] + sum_k w2[row0+j][k] * h_full[k]
    float acc[CHUNK];
    #pragma unroll
    for (int j = 0; j < CHUNK; ++j) acc[j] = b2[row0 + j];

    #pragma unroll 1   // keep the 4 gather phases rolled: I-cache friendly
    for (int d = 0; d < 4; ++d) {
        const int p = q ^ d;              // quarter whose h-chunk we consume
        const int col0 = p * CHUNK;
        float hb[CHUNK];
        #pragma unroll
        for (int i = 0; i < CHUNK; ++i) hb[i] = __shfl_xor(h[i], d * 16);
        const float* wbase = w2 + row0 * DIM + col0;
        #pragma unroll
        for (int j = 0; j < CHUNK; ++j) {
            const float* wrow = wbase + j * DIM;
            #pragma unroll
            for (int i = 0; i < CHUNK; ++i)
                acc[j] = fmaf(hb[i], wrow[i], acc[j]);
        }
    }

    // softplus + layer 3 partials, then reduce over the 4 quarters
    float p0 = 0.0f, p1 = 0.0f;
    #pragma unroll
    for (int j = 0; j < CHUNK; ++j) {
        float sp = fast_softplus(acc[j]);
        p0 = fmaf(w3[row0 + j], sp, p0);
        p1 = fmaf(w3[DIM + row0 + j], sp, p1);
    }
    p0 += __shfl_xor(p0, 16); p0 += __shfl_xor(p0, 32);
    p1 += __shfl_xor(p1, 16); p1 += __shfl_xor(p1, 32);
    o0 = p0 + b3[0];
    o1 = p1 + b3[1];
}

__global__ void __launch_bounds__(256, 4)
node_kernel(const float* __restrict__ y0,
            const float* __restrict__ tt,
            const float* __restrict__ fw1, const float* __restrict__ fb1,
            const float* __restrict__ fw2, const float* __restrict__ fb2,
            const float* __restrict__ fw3, const float* __restrict__ fb3,
            const float* __restrict__ gw1, const float* __restrict__ gb1,
            const float* __restrict__ gw2, const float* __restrict__ gb2,
            const float* __restrict__ gw3, const float* __restrict__ gb3,
            float* __restrict__ out)
{
    const int tid    = blockIdx.x * blockDim.x + threadIdx.x;
    const int lane   = threadIdx.x & 63;
    const int q      = lane >> 4;          // quarter within the wave
    const int m      = lane & 15;          // sample slot within the wave
    const int wave   = tid >> 6;
    const int sample = wave * 16 + m;      // 4096 waves * 16 samples = 65536

    const float dt = tt[1] - tt[0];

    float2 y = reinterpret_cast<const float2*>(y0)[sample];
    float ya = y.x, yb = y.y;

    float2* out2 = reinterpret_cast<float2*>(out);
    if (q == 0) out2[sample] = make_float2(ya, yb);   // out[0] = y0

    #pragma unroll 1
    for (int s = 1; s < T; ++s) {
        float u0, u1, f0, f1;
        mlp4<GHID, 13>(ya, yb, q, gw1, gb1, gw2, gb2, gw3, gb3, u0, u1);
        mlp4<HID, 16>(ya, yb, q, fw1, fb1, fw2, fb2, fw3, fb3, f0, f1);

        ya = fmaf(f0 + u0, dt, ya);
        yb = fmaf(f1 + u1, dt, yb);

        if (q == 0)
            out2[(size_t)s * BATCH + sample] = make_float2(ya, yb);
    }
}

extern "C" void kernel_launch(void* const* d_in, const int* in_sizes, int n_in,
                              void* d_out, int out_size, void* d_ws, size_t ws_size,
                              hipStream_t stream) {
    const float* y0  = (const float*)d_in[0];
    const float* tt  = (const float*)d_in[1];
    const float* fw1 = (const float*)d_in[2];
    const float* fb1 = (const float*)d_in[3];
    const float* fw2 = (const float*)d_in[4];
    const float* fb2 = (const float*)d_in[5];
    const float* fw3 = (const float*)d_in[6];
    const float* fb3 = (const float*)d_in[7];
    const float* gw1 = (const float*)d_in[8];
    const float* gb1 = (const float*)d_in[9];
    const float* gw2 = (const float*)d_in[10];
    const float* gb2 = (const float*)d_in[11];
    const float* gw3 = (const float*)d_in[12];
    const float* gb3 = (const float*)d_in[13];
    float* out = (float*)d_out;

    dim3 grid(BATCH * 4 / 256);   // 1024 blocks -> 4 blocks/CU -> 4 waves/SIMD
    dim3 block(256);
    hipLaunchKernelGGL(node_kernel, grid, block, 0, stream,
                       y0, tt, fw1, fb1, fw2, fb2, fw3, fb3,
                       gw1, gb1, gw2, gb2, gw3, gb3, out);
}

// Round 3
// 8491.386 us; speedup vs baseline: 3.8723x; 3.8723x over previous
//
#include <hip/hip_runtime.h>

#define BATCH 65536
#define T 500

typedef __attribute__((ext_vector_type(8))) short bf16x8;
typedef __attribute__((ext_vector_type(4))) float f32x4;
typedef __attribute__((ext_vector_type(2))) unsigned u32x2;

#define MFMA(A, B, C) __builtin_amdgcn_mfma_f32_16x16x32_bf16(A, B, C, 0, 0, 0)

__device__ __forceinline__ unsigned short f2bf(float x) {
    union { float f; unsigned u; } v; v.f = x;
    unsigned r = v.u + 0x7FFFu + ((v.u >> 16) & 1u);   // RNE
    return (unsigned short)(r >> 16);
}
__device__ __forceinline__ float bf2f(unsigned short b) {
    union { float f; unsigned u; } v; v.u = ((unsigned)b) << 16;
    return v.f;
}
__device__ __forceinline__ float fast_tanh(float x) {
    float e = __expf(2.0f * x);
    return 1.0f - 2.0f / (e + 1.0f);
}
__device__ __forceinline__ float fast_sp(float x) {
    float e = __expf(-fabsf(x));
    return fmaxf(x, 0.0f) + __logf(1.0f + e);
}
__device__ __forceinline__ void split2(float a, float b, unsigned& hi, unsigned& lo) {
    unsigned short ah = f2bf(a); float ar = a - bf2f(ah); unsigned short al = f2bf(ar);
    unsigned short bh = f2bf(b); float br = b - bf2f(bh); unsigned short bl = f2bf(br);
    hi = (unsigned)ah | ((unsigned)bh << 16);
    lo = (unsigned)al | ((unsigned)bl << 16);
}

// Split A-fragment (hi+lo bf16) for mfma_f32_16x16x32_bf16, tile (t,u) of
// row-major W[Mreal][Kreal] (stride Ks). A layout: row = lane&15 (+16t),
// k = (lane>>4)*8 + j (+32u)  [m92-verified contiguous-k]. If bias!=null,
// folds bias into column k==2 (layer-1 trick; K is padded anyway).
__device__ __forceinline__ void build_frag(const float* __restrict__ W,
                                           const float* __restrict__ bias,
                                           int Mreal, int Kreal, int Ks,
                                           int t, int u, int lane,
                                           bf16x8& hi, bf16x8& lo) {
    int row = t * 16 + (lane & 15);
    int kb = u * 32 + (lane >> 4) * 8;
    #pragma unroll
    for (int j = 0; j < 8; ++j) {
        int k = kb + j;
        float w = 0.0f;
        if (row < Mreal) {
            if (k < Kreal) w = W[row * Ks + k];
            else if (bias != nullptr && k == 2) w = bias[row];
        }
        unsigned short h = f2bf(w);
        float r = w - bf2f(h);
        hi[j] = (short)h;
        lo[j] = (short)f2bf(r);
    }
}

// act -> bf16x2 split -> LDS store (features contiguous per sample, stride 36 words)
template<bool TANH>
__device__ __forceinline__ void act_split_store(const f32x4* d,
                                                unsigned* ldsH, unsigned* ldsL,
                                                int wo_base, int G) {
    #pragma unroll
    for (int t = 0; t < 4; ++t) {
        float a0 = TANH ? fast_tanh(d[t][0]) : fast_sp(d[t][0]);
        float a1 = TANH ? fast_tanh(d[t][1]) : fast_sp(d[t][1]);
        float a2 = TANH ? fast_tanh(d[t][2]) : fast_sp(d[t][2]);
        float a3 = TANH ? fast_tanh(d[t][3]) : fast_sp(d[t][3]);
        unsigned h0, l0, h1, l1;
        split2(a0, a1, h0, l0);
        split2(a2, a3, h1, l1);
        int wo = wo_base + 8 * t + 2 * G;
        *reinterpret_cast<u32x2*>(&ldsH[wo]) = (u32x2){h0, h1};
        *reinterpret_cast<u32x2*>(&ldsL[wo]) = (u32x2){l0, l1};
    }
}

__device__ __forceinline__ void read_frags(const unsigned* ldsH, const unsigned* ldsL,
                                           int ro_base, int G, bf16x8* H, bf16x8* L) {
    #pragma unroll
    for (int u = 0; u < 2; ++u) {
        int ro = ro_base + 16 * u + 4 * G;
        H[u] = *reinterpret_cast<const bf16x8*>(&ldsH[ro]);
        L[u] = *reinterpret_cast<const bf16x8*>(&ldsL[ro]);
    }
}

__global__ void __launch_bounds__(256, 1)
node_kernel(const float* __restrict__ y0,
            const float* __restrict__ tt,
            const float* __restrict__ fw1, const float* __restrict__ fb1,
            const float* __restrict__ fw2, const float* __restrict__ fb2,
            const float* __restrict__ fw3, const float* __restrict__ fb3,
            const float* __restrict__ gw1, const float* __restrict__ gb1,
            const float* __restrict__ gw2, const float* __restrict__ gb2,
            const float* __restrict__ gw3, const float* __restrict__ gb3,
            float* __restrict__ out)
{
    __shared__ __align__(16) unsigned lds_fhi[4 * 576];
    __shared__ __align__(16) unsigned lds_flo[4 * 576];
    __shared__ __align__(16) unsigned lds_ghi[4 * 576];
    __shared__ __align__(16) unsigned lds_glo[4 * 576];
    __shared__ float lds_y[4 * 4 * 16 * 2];

    const int lane = threadIdx.x & 63;
    const int wIdx = threadIdx.x >> 6;
    const int waveG = blockIdx.x * 4 + wIdx;
    const int c = lane & 15;
    const int G = lane >> 4;
    const bool lo16 = (lane < 16);
    const int fbase = wIdx * 576;
    const int cb = fbase + c * 36;

    const float dt = tt[1] - tt[0];

    // ---- persistent split weight fragments (built once, live 499 steps) ----
    bf16x8 fw1h[4], fw1l[4], gw1h[4], gw1l[4];
    bf16x8 fw2h[4][2], fw2l[4][2], gw2h[4][2], gw2l[4][2];
    bf16x8 fw3h[2], fw3l[2], gw3h[2], gw3l[2];
    #pragma unroll
    for (int t = 0; t < 4; ++t) {
        build_frag(fw1, fb1, 64, 2, 2, t, 0, lane, fw1h[t], fw1l[t]);
        build_frag(gw1, gb1, 52, 2, 2, t, 0, lane, gw1h[t], gw1l[t]);
        #pragma unroll
        for (int u = 0; u < 2; ++u) {
            build_frag(fw2, nullptr, 64, 64, 64, t, u, lane, fw2h[t][u], fw2l[t][u]);
            build_frag(gw2, nullptr, 52, 52, 52, t, u, lane, gw2h[t][u], gw2l[t][u]);
        }
    }
    #pragma unroll
    for (int u = 0; u < 2; ++u) {
        build_frag(fw3, nullptr, 2, 64, 64, 0, u, lane, fw3h[u], fw3l[u]);
        build_frag(gw3, nullptr, 2, 52, 52, 0, u, lane, gw3h[u], gw3l[u]);
    }
    // layer-2 biases as mfma C-init (D row = 16t + 4G + reg)
    f32x4 fb2c[4], gb2c[4];
    #pragma unroll
    for (int t = 0; t < 4; ++t) {
        #pragma unroll
        for (int r = 0; r < 4; ++r) {
            int row = 16 * t + 4 * G + r;
            fb2c[t][r] = fb2[row];
            gb2c[t][r] = (row < 52) ? gb2[row] : 0.0f;
        }
    }
    f32x4 fb3c = { lo16 ? fb3[0] : 0.0f, lo16 ? fb3[1] : 0.0f, 0.0f, 0.0f };
    f32x4 gb3c = { lo16 ? gb3[0] : 0.0f, lo16 ? gb3[1] : 0.0f, 0.0f, 0.0f };
    const f32x4 zero4 = { 0.0f, 0.0f, 0.0f, 0.0f };

    // ---- y0 init: LDS y state + out[0] ----
    #pragma unroll 1
    for (int ct = 0; ct < 4; ++ct) {
        int sample = waveG * 64 + ct * 16 + c;
        int yoff = ((wIdx * 4 + ct) * 16 + c) * 2;
        if (lo16) {
            float2 yv = reinterpret_cast<const float2*>(y0)[sample];
            lds_y[yoff] = yv.x; lds_y[yoff + 1] = yv.y;
            reinterpret_cast<float2*>(out)[sample] = yv;
        }
    }

    // ---- time loop ----
    #pragma unroll 1
    for (int s = 1; s < T; ++s) {
        #pragma unroll 1
        for (int ct = 0; ct < 4; ++ct) {
            const int yoff = ((wIdx * 4 + ct) * 16 + c) * 2;
            float ya = lds_y[yoff], yb = lds_y[yoff + 1];

            // y 3-split -> B fragments (k=0:ya, k=1:yb, k=2:1.0 bias col; lanes>=16 zero)
            unsigned short yah = f2bf(ya); float yar = ya - bf2f(yah);
            unsigned short yam = f2bf(yar); float yar2 = yar - bf2f(yam);
            unsigned short yal = f2bf(yar2);
            unsigned short ybh = f2bf(yb); float ybr = yb - bf2f(ybh);
            unsigned short ybm = f2bf(ybr); float ybr2 = ybr - bf2f(ybm);
            unsigned short ybl = f2bf(ybr2);
            bf16x8 yH = {0,0,0,0,0,0,0,0}, yM = {0,0,0,0,0,0,0,0}, yL = {0,0,0,0,0,0,0,0};
            if (lo16) {
                yH[0] = (short)yah; yH[1] = (short)ybh; yH[2] = (short)0x3F80; // 1.0
                yM[0] = (short)yam; yM[1] = (short)ybm;
                yL[0] = (short)yal; yL[1] = (short)ybl;
            }

            // ---- layer 1 (K=2 + bias col, 5 split passes) ----
            f32x4 d1f[4], d1g[4];
            #pragma unroll
            for (int t = 0; t < 4; ++t) {
                f32x4 a = MFMA(fw1h[t], yH, zero4);
                a = MFMA(fw1h[t], yM, a);
                a = MFMA(fw1h[t], yL, a);
                a = MFMA(fw1l[t], yH, a);
                d1f[t] = MFMA(fw1l[t], yM, a);
            }
            act_split_store<true>(d1f, lds_fhi, lds_flo, cb, G);
            #pragma unroll
            for (int t = 0; t < 4; ++t) {
                f32x4 a = MFMA(gw1h[t], yH, zero4);
                a = MFMA(gw1h[t], yM, a);
                a = MFMA(gw1h[t], yL, a);
                a = MFMA(gw1l[t], yH, a);
                d1g[t] = MFMA(gw1l[t], yM, a);
            }
            act_split_store<true>(d1g, lds_ghi, lds_glo, cb, G);

            // ---- layer 2 (K=64, 3 split passes, bias as C-init) ----
            bf16x8 fhH[2], fhL[2], ghH[2], ghL[2];
            read_frags(lds_fhi, lds_flo, cb, G, fhH, fhL);
            f32x4 d2f[4], d2g[4];
            #pragma unroll
            for (int t = 0; t < 4; ++t) {
                f32x4 a = fb2c[t];
                #pragma unroll
                for (int u = 0; u < 2; ++u) {
                    a = MFMA(fw2h[t][u], fhH[u], a);
                    a = MFMA(fw2h[t][u], fhL[u], a);
                    a = MFMA(fw2l[t][u], fhH[u], a);
                }
                d2f[t] = a;
            }
            read_frags(lds_ghi, lds_glo, cb, G, ghH, ghL);
            #pragma unroll
            for (int t = 0; t < 4; ++t) {
                f32x4 a = gb2c[t];
                #pragma unroll
                for (int u = 0; u < 2; ++u) {
                    a = MFMA(gw2h[t][u], ghH[u], a);
                    a = MFMA(gw2h[t][u], ghL[u], a);
                    a = MFMA(gw2l[t][u], ghH[u], a);
                }
                d2g[t] = a;
            }

            // ---- softplus + resplit (reuse LDS buffers) ----
            act_split_store<false>(d2f, lds_fhi, lds_flo, cb, G);
            act_split_store<false>(d2g, lds_ghi, lds_glo, cb, G);

            // ---- layer 3 (rows 0,1 real) ----
            bf16x8 f2H[2], f2L[2], g2H[2], g2L[2];
            read_frags(lds_fhi, lds_flo, cb, G, f2H, f2L);
            f32x4 d3f = fb3c;
            #pragma unroll
            for (int u = 0; u < 2; ++u) {
                d3f = MFMA(fw3h[u], f2H[u], d3f);
                d3f = MFMA(fw3h[u], f2L[u], d3f);
                d3f = MFMA(fw3l[u], f2H[u], d3f);
            }
            read_frags(lds_ghi, lds_glo, cb, G, g2H, g2L);
            f32x4 d3g = gb3c;
            #pragma unroll
            for (int u = 0; u < 2; ++u) {
                d3g = MFMA(gw3h[u], g2H[u], d3g);
                d3g = MFMA(gw3h[u], g2L[u], d3g);
                d3g = MFMA(gw3l[u], g2H[u], d3g);
            }

            // ---- Euler update + store (y of sample c lives in lanes 0-15) ----
            if (lo16) {
                float nya = fmaf(d3f[0] + d3g[0], dt, ya);
                float nyb = fmaf(d3f[1] + d3g[1], dt, yb);
                lds_y[yoff] = nya; lds_y[yoff + 1] = nyb;
                int sample = waveG * 64 + ct * 16 + c;
                reinterpret_cast<float2*>(out)[(size_t)s * BATCH + sample] =
                    make_float2(nya, nyb);
            }
        }
    }
}

extern "C" void kernel_launch(void* const* d_in, const int* in_sizes, int n_in,
                              void* d_out, int out_size, void* d_ws, size_t ws_size,
                              hipStream_t stream) {
    const float* y0  = (const float*)d_in[0];
    const float* tt  = (const float*)d_in[1];
    const float* fw1 = (const float*)d_in[2];
    const float* fb1 = (const float*)d_in[3];
    const float* fw2 = (const float*)d_in[4];
    const float* fb2 = (const float*)d_in[5];
    const float* fw3 = (const float*)d_in[6];
    const float* fb3 = (const float*)d_in[7];
    const float* gw1 = (const float*)d_in[8];
    const float* gb1 = (const float*)d_in[9];
    const float* gw2 = (const float*)d_in[10];
    const float* gb2 = (const float*)d_in[11];
    const float* gw3 = (const float*)d_in[12];
    const float* gb3 = (const float*)d_in[13];
    float* out = (float*)d_out;

    dim3 grid(BATCH / 256);   // 256 blocks x 4 waves = 1024 waves, 64 samples/wave
    dim3 block(256);
    hipLaunchKernelGGL(node_kernel, grid, block, 0, stream,
                       y0, tt, fw1, fb1, fw2, fb2, fw3, fb3,
                       gw1, gb1, gw2, gb2, gw3, gb3, out);
}